// Round 2
// baseline (3354.053 us; speedup 1.0000x reference)
//
#include <hip/hip_runtime.h>
#include <math.h>

#define BATCH 32
#define TFRAMES 1024
#define NBINS 257
#define HOP 160
#define LOUT 163680
#define XPLEN 164192
#define NITER 32
#define BSTRIDE 1280              // 8 frames * HOP per block
#define HALO 352                  // NFFT - HOP
#define SPAN (BSTRIDE+HALO)       // 1632 floats per-block OLA span
#define NBLK 128                  // blocks per batch row
#define SLOT SPAN
#define SB ((size_t)NBLK*SLOT)
#define SBUF ((size_t)BATCH*SB)
#define GSTRIDE 264               // float2 stride of per-frame LDS sub-buffer

__device__ __forceinline__ float cosr(float x){ return __builtin_amdgcn_cosf(x); }
__device__ __forceinline__ float sinr(float x){ return __builtin_amdgcn_sinf(x); }
__device__ __forceinline__ void wsync(){
    __builtin_amdgcn_fence(__ATOMIC_SEQ_CST, "wavefront");
    __builtin_amdgcn_wave_barrier();
}
__device__ __forceinline__ float bperm(int addr, float v){
    return __int_as_float(__builtin_amdgcn_ds_bpermute(addr, __float_as_int(v)));
}

// radix-4 butterfly, no twiddle: y_k = sum_j x_j * W4^{SIGN*j*k}
template<int SIGN>
__device__ __forceinline__ void bfly4n(const float xr[4], const float xi[4],
                                       float yr[4], float yi[4]){
    constexpr float SG = (SIGN>0)?1.f:-1.f;
    float apc_r=xr[0]+xr[2], apc_i=xi[0]+xi[2];
    float amc_r=xr[0]-xr[2], amc_i=xi[0]-xi[2];
    float bpd_r=xr[1]+xr[3], bpd_i=xi[1]+xi[3];
    float bmd_r=xr[1]-xr[3], bmd_i=xi[1]-xi[3];
    yr[0]=apc_r+bpd_r; yi[0]=apc_i+bpd_i;
    yr[2]=apc_r-bpd_r; yi[2]=apc_i-bpd_i;
    yr[1]=amc_r-SG*bmd_i; yi[1]=amc_i+SG*bmd_r;
    yr[3]=amc_r+SG*bmd_i; yi[3]=amc_i-SG*bmd_r;
}

// 16-pt DFT fully in registers, natural order in and out:
// z_out[k] = sum_n z_in[n] * W16^{SIGN*n*k}. All twiddles compile-time.
template<int SIGN>
__device__ __forceinline__ void fft16(float zr[16], float zi[16]){
    constexpr float SG = (SIGN>0)?1.f:-1.f;
    constexpr float CT16[16] = { 1.f, 0.9238795325f, 0.7071067812f, 0.3826834324f,
                                 0.f,-0.3826834324f,-0.7071067812f,-0.9238795325f,
                                -1.f,-0.9238795325f,-0.7071067812f,-0.3826834324f,
                                 0.f, 0.3826834324f, 0.7071067812f, 0.9238795325f};
    constexpr float ST16[16] = { 0.f, 0.3826834324f, 0.7071067812f, 0.9238795325f,
                                 1.f, 0.9238795325f, 0.7071067812f, 0.3826834324f,
                                 0.f,-0.3826834324f,-0.7071067812f,-0.9238795325f,
                                -1.f,-0.9238795325f,-0.7071067812f,-0.3826834324f};
    float ur[16], ui[16];
    // stage 1: n = 4a + b; radix-4 over a for each b, then W16^{SIGN*b*c}
#pragma unroll
    for (int bq=0;bq<4;++bq){
        float xr4[4]={zr[bq],zr[bq+4],zr[bq+8],zr[bq+12]};
        float xi4[4]={zi[bq],zi[bq+4],zi[bq+8],zi[bq+12]};
        float yr4[4], yi4[4];
        bfly4n<SIGN>(xr4,xi4,yr4,yi4);
#pragma unroll
        for (int c=0;c<4;++c){
            float vr=yr4[c], vi=yi4[c];
            int J = (bq*c)&15;                 // compile-time after unroll
            if (J==4){ float tv=vr; vr=-SG*vi; vi=SG*tv; }
            else if (J!=0){
                float tr2 = CT16[J]*vr - SG*ST16[J]*vi;
                vi        = CT16[J]*vi + SG*ST16[J]*vr;
                vr = tr2;
            }
            ur[4*c+bq]=vr; ui[4*c+bq]=vi;
        }
    }
    // stage 2: k = c + 4d; radix-4 over b for each c
#pragma unroll
    for (int c=0;c<4;++c){
        float xr4[4]={ur[4*c],ur[4*c+1],ur[4*c+2],ur[4*c+3]};
        float xi4[4]={ui[4*c],ui[4*c+1],ui[4*c+2],ui[4*c+3]};
        float yr4[4], yi4[4];
        bfly4n<SIGN>(xr4,xi4,yr4,yi4);
#pragma unroll
        for (int d=0;d<4;++d){ zr[c+4*d]=yr4[d]; zi[c+4*d]=yi4[d]; }
    }
}

// 256-pt FFT per 16-lane group: 16 complex values per lane.
// In:  index n = 16*reg + (lane&15).  Out: index k = (lane&15) + 16*reg.
// tb: group-private 264-float2 LDS sub-buffer (16x16 transpose, XOR-swizzled cols).
template<int SIGN>
__device__ __forceinline__ void fft256_16(float zr[16], float zi[16],
                                          float2* __restrict__ tb, int k1l){
    constexpr float SG = (SIGN>0)?1.f:-1.f;
    fft16<SIGN>(zr, zi);                       // over high digit (regs)
    float k1f = (float)k1l;
#pragma unroll
    for (int r=1;r<16;++r){                    // W256^{SIGN * n2 * k1}, n2 = lane&15
        float aa = k1f * ((float)r * (1.0f/256.0f));   // revolutions, < 0.88
        float tc = cosr(aa), ts = SG*sinr(aa);
        float tr2 = tc*zr[r] - ts*zi[r];
        zi[r]     = tc*zi[r] + ts*zr[r];
        zr[r] = tr2;
    }
    // 16x16 transpose within the group; column XOR-swizzle kills the
    // row-broadcast (all-lanes-same-bank) conflict on the read side.
#pragma unroll
    for (int r=0;r<16;++r) tb[16*r + (k1l ^ r)] = make_float2(zr[r], zi[r]);
    wsync();
    float tr[16], ti[16];
#pragma unroll
    for (int c=0;c<16;++c){ float2 v = tb[16*k1l + (c ^ k1l)]; tr[c]=v.x; ti[c]=v.y; }
    wsync();
    fft16<SIGN>(tr, ti);                       // over low digit (now regs)
#pragma unroll
    for (int c=0;c<16;++c){ zr[c]=tr[c]; zi[c]=ti[c]; }
}

// ============================================================
__global__ __launch_bounds__(256) void k_init(const float* __restrict__ win,
                                              float* __restrict__ wsqi){
    int i = blockIdx.x*256 + threadIdx.x;
    if (i < XPLEN){
        int n = i;
        int tmax = n / HOP; if (tmax > TFRAMES-1) tmax = TFRAMES-1;
        int tmin = (n - 511 + (HOP-1)) / HOP; if (tmin < 0) tmin = 0;
        float acc = 0.f;
        for (int t = tmin; t <= tmax; ++t){ float w = win[n - t*HOP]; acc += w*w; }
        wsqi[i] = 1.0f / (acc > 1e-11f ? acc : 1.0f);
    }
}

// slot-reconstructed signal reads
__device__ __forceinline__ float xs(const float* __restrict__ Sb,
                                    const float* __restrict__ wsq, int p){
    int bxp = p / BSTRIDE, r = p - bxp*BSTRIDE;
    float a = 0.f;
    if (bxp < NBLK) a = Sb[(size_t)bxp*SLOT + r];
    if (r < HALO && bxp > 0) a += Sb[(size_t)(bxp-1)*SLOT + BSTRIDE + r];
    return a * wsq[p];
}
__device__ __forceinline__ float2 xs2(const float* __restrict__ Sb,
                                      const float* __restrict__ wsq, int p){ // p even
    int bxp = p / BSTRIDE, r = p - bxp*BSTRIDE;
    float2 acc = make_float2(0.f, 0.f);
    if (bxp < NBLK) acc = *(const float2*)(Sb + (size_t)bxp*SLOT + r);
    if (r < HALO && bxp > 0){
        float2 h = *(const float2*)(Sb + (size_t)(bxp-1)*SLOT + BSTRIDE + r);
        acc.x += h.x; acc.y += h.y;
    }
    float2 q = *(const float2*)(wsq + p);
    return make_float2(acc.x*q.x, acc.y*q.y);
}

// window + scale -> per-frame LDS buffer; then block OLA -> slot
__device__ __forceinline__ void tail_store(const float zr[16], const float zi[16],
                                           const float2* WL, float2* tb,
                                           const float2* XB,
                                           float* __restrict__ Sw,
                                           int b, int bx, int tid, int k1l){
    constexpr float SC = 1.f/256.f;
#pragma unroll
    for (int c=0;c<16;++c){
        int m = k1l + 16*c;                 // time pair index within frame
        float2 wv = WL[m];
        tb[m] = make_float2(zr[c]*wv.x*SC, zi[c]*wv.y*SC);
    }
    __syncthreads();
    float2* slot2 = (float2*)(Sw + ((size_t)b*NBLK + bx)*SLOT);
#pragma unroll
    for (int j=0;j<7;++j){
        int u = tid + 128*j;
        if (u < SPAN/2){
            float2 acc = make_float2(0.f, 0.f);
            int f1 = u/80;            if (f1 > 7) f1 = 7;
            int f0 = (u - 176)/80;    if (f0 < 0) f0 = 0;   // ceil((u-255)/80)
            for (int f = f0; f <= f1; ++f){
                float2 v = XB[f*GSTRIDE + (u - 80*f)];
                acc.x += v.x; acc.y += v.y;
            }
            slot2[u] = acc;
        }
    }
}

// ============================================================
// k_gl: one Griffin-Lim iteration. 128 thr = 2 waves; each 16-lane
// group owns one frame -> 4 frames per wave concurrently in flight.
// ============================================================
__global__ __launch_bounds__(128,3) void k_gl(const float* __restrict__ Sr,
                                              float* __restrict__ Sw,
                                              const float* __restrict__ mag,
                                              const float* __restrict__ win,
                                              const float* __restrict__ wsq){
    __shared__ __align__(16) float2 XB[8*GSTRIDE];   // transpose bufs, reused as frame bufs
    __shared__ __align__(16) float2 WL[256];         // window pairs
    int tid = threadIdx.x, w = tid>>6, lane = tid&63;
    int g = lane>>4, k1l = lane&15;
    int b = blockIdx.y, bx = blockIdx.x;

    WL[tid]     = ((const float2*)win)[tid];
    WL[tid+128] = ((const float2*)win)[tid+128];
    __syncthreads();

    int fidx = 4*w + g;
    int t = bx*8 + fidx;
    float2* tb = XB + fidx*GSTRIDE;
    const float* Sb   = Sr  + (size_t)b*SB;
    const float* magp = mag + ((size_t)b*TFRAMES + (size_t)t)*NBINS;

    // ---- load frame (packed even/odd, windowed): z[n], n = 16*reg + k1l
    float zr[16], zi[16];
    bool edge = (t < 2) | (t >= TFRAMES-2);
    if (!edge){
        int pb = t*HOP;
#pragma unroll
        for (int r=0;r<16;++r){
            int m = 16*r + k1l;
            float2 v = xs2(Sb, wsq, pb + 2*m);
            float2 wv = WL[m];
            zr[r] = v.x*wv.x; zi[r] = v.y*wv.y;
        }
    } else {
#pragma unroll
        for (int r=0;r<16;++r){
            int m = 16*r + k1l;
            int p0 = t*HOP + 2*m, p1 = p0+1;
            int n0 = (p0<256)?(512-p0):((p0>=LOUT+256)?(2*LOUT+510-p0):p0);
            int n1 = (p1<256)?(512-p1):((p1>=LOUT+256)?(2*LOUT+510-p1):p1);
            float2 wv = WL[m];
            zr[r] = xs(Sb, wsq, n0)*wv.x;
            zi[r] = xs(Sb, wsq, n1)*wv.y;
        }
    }

    // ---- forward FFT: Z[k] at (lane=k&15, reg=k>>4)
    fft256_16<-1>(zr, zi, tb, k1l);

    // ---- mirror Y[c] = Z[(256-k)&255], k = k1l + 16c  (intra-group bpermute)
    int pl = (lane & 48) | ((16 - k1l) & 15);
    int am = pl << 2;
    bool l0 = (k1l == 0);
    float yr[16], yi[16];
#pragma unroll
    for (int c=0;c<16;++c){
        float gr = bperm(am, zr[15-c]);
        float gi = bperm(am, zi[15-c]);
        yr[c] = l0 ? zr[(16-c)&15] : gr;
        yi[c] = l0 ? zi[(16-c)&15] : gi;
    }

    // ---- spectral projection (r6-verbatim math), in-place into z
    float a0 = (float)k1l * (1.0f/512.0f);
#pragma unroll
    for (int c=0;c<16;++c){
        float aa = a0 + (float)c*(1.0f/32.0f);
        float tc = cosr(aa), ts = sinr(aa);
        float zrr = zr[c], zii = zi[c];
        float Xer = 0.5f*(zrr+yr[c]), Xei = 0.5f*(zii-yi[c]);
        float Dr = zrr-yr[c], Di = zii+yi[c];
        float Xor = 0.5f*Di, Xoi = -0.5f*Dr;
        float Or = tc*Xor + ts*Xoi;
        float Oi = tc*Xoi - ts*Xor;
        float X1r = Xer + Or, X1i = Xei + Oi;
        float X2r = Xer - Or, X2i = Oi - Xei;
        float q1 = X1r*X1r + X1i*X1i;
        bool ok1 = q1 > 1e-30f;
        float v1 = ok1 ? __builtin_amdgcn_rsqf(q1) : 0.f;
        float c1 = ok1 ? X1r*v1 : 1.f, s1 = X1i*v1;
        float q2 = X2r*X2r + X2i*X2i;
        bool ok2 = q2 > 1e-30f;
        float v2 = ok2 ? __builtin_amdgcn_rsqf(q2) : 0.f;
        float c2 = ok2 ? X2r*v2 : 1.f, s2 = X2i*v2;
        int k = k1l + 16*c;
        float m1 = magp[k], m2 = magp[256-k];
        float S1r = m1*c1, S1i = m1*s1;
        float S2r = m2*c2, S2i = m2*s2;
        float Aer = 0.5f*(S1r+S2r), Aei = 0.5f*(S1i-S2i);
        float Er = S1r - S2r, Ei = S1i + S2i;
        float Bor = 0.5f*(tc*Er - ts*Ei);
        float Boi = 0.5f*(tc*Ei + ts*Er);
        zr[c] = Aer - Boi;
        zi[c] = Aei + Bor;
    }

    // ---- inverse FFT: time pairs at m = k1l + 16*reg
    fft256_16<+1>(zr, zi, tb, k1l);

    tail_store(zr, zi, WL, tb, XB, Sw, b, bx, tid, k1l);
}

// ============================================================
// k_inv0s: iteration-0 istft from (mag, angles_init) -> slots
// ============================================================
__global__ __launch_bounds__(128,3) void k_inv0s(const float* __restrict__ mag,
                                                 const float* __restrict__ ang,
                                                 const float* __restrict__ win,
                                                 float* __restrict__ Sw){
    __shared__ __align__(16) float2 XB[8*GSTRIDE];
    __shared__ __align__(16) float2 WL[256];
    int tid = threadIdx.x, w = tid>>6, lane = tid&63;
    int g = lane>>4, k1l = lane&15;
    int b = blockIdx.y, bx = blockIdx.x;

    WL[tid]     = ((const float2*)win)[tid];
    WL[tid+128] = ((const float2*)win)[tid+128];
    __syncthreads();

    int fidx = 4*w + g;
    int t = bx*8 + fidx;
    float2* tb = XB + fidx*GSTRIDE;
    const float* magp = mag + ((size_t)b*TFRAMES + (size_t)t)*NBINS;
    const float* angp = ang + ((size_t)b*TFRAMES + (size_t)t)*NBINS;

    int pl = (lane & 48) | ((16 - k1l) & 15);
    int am = pl << 2;
    bool l0 = (k1l == 0);

    // ---- S[k] at (lane=k&15, reg=k>>4); Im(S[0]) zeroed (irfft semantics)
    float zr[16], zi[16];
#pragma unroll
    for (int r=0;r<16;++r){
        int k = 16*r + k1l;
        float m = magp[k], an = angp[k];
        float sn, cs;
        sincosf(an, &sn, &cs);
        zr[r] = m*cs;
        zi[r] = ((r==0) && l0) ? 0.f : m*sn;
    }
    float nyr = magp[256]*cosf(angp[256]);    // Nyquist (imag zeroed)

    // ---- mirror S[256-k]
    float yr[16], yi[16];
#pragma unroll
    for (int c=0;c<16;++c){
        float gr = bperm(am, zr[15-c]);
        float gi = bperm(am, zi[15-c]);
        float lr = (c==0) ? nyr : zr[(16-c)&15];
        float li = (c==0) ? 0.f : zi[(16-c)&15];
        yr[c] = l0 ? lr : gr;
        yi[c] = l0 ? li : gi;
    }

    // ---- c2r pack -> P
    float a0 = (float)k1l * (1.0f/512.0f);
#pragma unroll
    for (int c=0;c<16;++c){
        float aa = a0 + (float)c*(1.0f/32.0f);
        float tc = cosr(aa), ts = sinr(aa);
        float sr = zr[c], si = zi[c];
        float Aer = 0.5f*(sr + yr[c]), Aei = 0.5f*(si - yi[c]);
        float Er = sr - yr[c], Ei = si + yi[c];
        float Bor = 0.5f*(tc*Er - ts*Ei);
        float Boi = 0.5f*(tc*Ei + ts*Er);
        zr[c] = Aer - Boi;
        zi[c] = Aei + Bor;
    }

    fft256_16<+1>(zr, zi, tb, k1l);

    tail_store(zr, zi, WL, tb, XB, Sw, b, bx, tid, k1l);
}

// ============================================================
__global__ __launch_bounds__(128) void k_out(const float* __restrict__ S,
                                             const float* __restrict__ wsq,
                                             float* __restrict__ out){
    int b = blockIdx.y;
    int idx = blockIdx.x*128 + threadIdx.x;
    if (idx >= LOUT/2) return;
    const float* Sb = S + (size_t)b*SB;
    float2 v = xs2(Sb, wsq, 256 + 2*idx);
    ((float2*)(out + (size_t)b*LOUT))[idx] = v;
}

// ============================================================
extern "C" void kernel_launch(void* const* d_in, const int* in_sizes, int n_in,
                              void* d_out, int out_size, void* d_ws, size_t ws_size,
                              hipStream_t stream) {
    const float* mag  = (const float*)d_in[0];
    const float* ang0 = (const float*)d_in[1];
    const float* win  = (const float*)d_in[2];
    float* ws = (float*)d_ws;
    float* S[2] = { ws, ws + SBUF };
    float* wsqi = ws + 2*SBUF;
    float* outp = (float*)d_out;

    k_init<<<(XPLEN + 255)/256, 256, 0, stream>>>(win, wsqi);

    dim3 g(NBLK, BATCH);
    k_inv0s<<<g, 128, 0, stream>>>(mag, ang0, win, S[0]);
    for (int it = 0; it < NITER; ++it){
        k_gl<<<g, 128, 0, stream>>>(S[it%2], S[(it+1)%2], mag, win, wsqi);
    }
    k_out<<<dim3(640, BATCH), 128, 0, stream>>>(S[NITER%2], wsqi, outp);
}